// Round 8
// baseline (64.524 us; speedup 1.0000x reference)
//
#include <hip/hip_runtime.h>
#include <hip/hip_bf16.h>
#include <math.h>

#define NB 2
#define NT 256
#define NN 512
#define NH 64
#define NS 8
#define NC 8

// workspace layout (float offsets)
#define OFF_H      0                    // 2*512*64 = 65536
#define OFF_PVEC   65536                // 65536   (pre_i + be1)
#define OFF_INVN   131072               // 1024
#define OFF_WA     132096               // 4096 shorts = 2048 floats (Wa bf16 frags)
#define OFF_WJF    134144               // 4096 floats (Wj f32, frag order)
#define OFF_WPF    138240               // 4096 floats (Wp f32, frag order)
#define OFF_UNSYM  142336               // 2*512*512 = 524288
#define OFF_LOGIT  (142336 + 524288)    // 2*512*512 = 524288

typedef __attribute__((ext_vector_type(8))) short short8;
typedef __attribute__((ext_vector_type(4))) float f32x4;
typedef __attribute__((ext_vector_type(4))) unsigned uint4v;

__device__ __forceinline__ float softplusf(float x){
  if (x > 20.f) return x;
  return log1pf(expf(x));
}

__device__ __forceinline__ short f2bf(float x){
  __hip_bfloat16 h = __float2bfloat16(x);
  return __builtin_bit_cast(short, h);
}

// single-instruction packed f32->bf16x2 (gfx950)
__device__ __forceinline__ unsigned cvtpk(float a, float b){
  unsigned r;
  asm("v_cvt_pk_bf16_f32 %0, %1, %2" : "=v"(r) : "v"(a), "v"(b));
  return r;
}

__device__ __forceinline__ void keep8(short8 &v){
  asm volatile("" : "+v"(v));
}

template<int CTRL>
__device__ __forceinline__ float dpp_addf(float x){
  int xi = __builtin_bit_cast(int, x);
  int yi = __builtin_amdgcn_update_dpp(0, xi, CTRL, 0xF, 0xF, true);
  return x + __builtin_bit_cast(float, yi);
}
__device__ __forceinline__ float row16_sum(float x){
  x = dpp_addf<0xB1>(x);    // lane^1
  x = dpp_addf<0x4E>(x);    // lane^2
  x = dpp_addf<0x141>(x);   // lane^7 (row_half_mirror)
  x = dpp_addf<0x140>(x);   // lane^15 (row_mirror)
  return x;
}

// ---------------- Kernel FRONT (unchanged from r7) ----------------
__global__ __launch_bounds__(256) void k_front(
    const float* __restrict__ x, const float* __restrict__ mask,
    const float* __restrict__ sctx,
    const float* __restrict__ W1, const float* __restrict__ b1,
    const float* __restrict__ W2, const float* __restrict__ b2,
    const float* __restrict__ We1, const float* __restrict__ be1,
    float* __restrict__ hg, float* __restrict__ pvec,
    float* __restrict__ invn, short* __restrict__ wa_bf,
    float* __restrict__ wjf, float* __restrict__ wpf){
  int blk = blockIdx.x;
  int tid = threadIdx.x;

  if (blk >= 256){
    int pidx = (blk - 256)*256 + tid;        // 0..12287
    int e    = pidx & 7;
    int lane = (pidx >> 3) & 63;
    int frag = (pidx >> 9) & 7;              // ks*4+nt
    int nt = frag & 3, ks = frag >> 2;
    int kg = lane >> 4, q = lane & 15;
    int kk = ks*32 + kg*8 + e;
    int c  = nt*16 + q;
    if (pidx < 4096){
      wa_bf[pidx] = f2bf(We1[(128 + kk)*NH + c]);
    } else if (pidx < 8192){
      wjf[pidx - 4096] = We1[(64 + kk)*NH + c];
    } else {
      wpf[pidx - 8192] = We1[(192 + kk)*NH + c];
    }
    return;
  }

  int b  = blk >> 7;
  int n0 = (blk & 127) * 4;

  int nl = tid & 3;
  int ts = tid >> 2;
  int n  = n0 + nl;

  float cnt = 0.f, sx = 0.f, sxx = 0.f;
  int lastt = 0;
  for (int t = ts*4; t < ts*4 + 4; ++t){
    int idx = (b*NT + t)*NN + n;
    float xv = x[idx];
    float mv = mask[idx];
    bool obs = (mv < 0.5f);
    if (obs){ cnt += 1.f; sx += xv; sxx += xv*xv; lastt = t; }
  }
  #pragma unroll
  for (int m = 4; m < 64; m <<= 1){
    cnt   += __shfl_xor(cnt,  m);
    sx    += __shfl_xor(sx,   m);
    sxx   += __shfl_xor(sxx,  m);
    lastt  = max(lastt, __shfl_xor(lastt, m));
  }
  int w = tid >> 6;
  __shared__ float r_cnt[4][4], r_sx[4][4], r_sxx[4][4];
  __shared__ int   r_lt[4][4];
  __shared__ float s_dyn[4][4];
  if ((tid & 63) < 4){
    r_cnt[w][nl] = cnt; r_sx[w][nl] = sx; r_sxx[w][nl] = sxx; r_lt[w][nl] = lastt;
  }
  __syncthreads();
  if (tid < 4){
    float c = 0.f, s1 = 0.f, s2 = 0.f; int lt = 0;
    #pragma unroll
    for (int ww = 0; ww < 4; ++ww){
      c  += r_cnt[ww][tid]; s1 += r_sx[ww][tid]; s2 += r_sxx[ww][tid];
      lt  = max(lt, r_lt[ww][tid]);
    }
    float cc   = fmaxf(c, 1.f);
    float mean = s1 / cc;
    float var  = s2 / cc - mean*mean;
    float stdv = sqrtf(fmaxf(var, 0.f) + 1e-6f);
    float last = x[(b*NT + lt)*NN + n0 + tid];
    float mr   = 1.f - c * (1.f/(float)NT);
    s_dyn[tid][0] = mean; s_dyn[tid][1] = stdv; s_dyn[tid][2] = last; s_dyn[tid][3] = mr;
  }
  __syncthreads();

  int c = tid & 63;
  int gn = n0 + w;
  int bn = b*NN + gn;
  __shared__ float s_f[4][12];
  __shared__ float s_h1[4][64];
  __shared__ float s_h2[4][64];

  if (c < 4)       s_f[w][c] = s_dyn[w][c];
  else if (c < 12) s_f[w][c] = sctx[gn*NS + (c-4)];
  __syncthreads();

  float a = b1[c];
  #pragma unroll
  for (int k = 0; k < 12; ++k) a = fmaf(s_f[w][k], W1[k*NH + c], a);
  s_h1[w][c] = fmaxf(a, 0.f);
  __syncthreads();

  float a2 = b2[c];
  #pragma unroll 8
  for (int k = 0; k < 64; ++k) a2 = fmaf(s_h1[w][k], W2[k*NH + c], a2);
  a2 = fmaxf(a2, 0.f);

  float sq = a2*a2;
  #pragma unroll
  for (int m = 1; m < 64; m <<= 1) sq += __shfl_xor(sq, m);
  float inv = 1.f / fmaxf(sqrtf(sq), 1e-12f);

  s_h2[w][c] = a2;
  __syncthreads();

  float pi = be1[c];
  #pragma unroll 8
  for (int k = 0; k < 64; ++k) pi = fmaf(s_h2[w][k], We1[k*NH + c], pi);

  hg  [bn*64 + c] = a2;
  pvec[bn*64 + c] = pi;
  if (c == 0) invn[bn] = inv;
}

// ---------------- Kernel L: pairwise edge logits (no softmax) ----------------
// grid NB*NN, 512 thr = 8 waves; wave handles tiles it = w, w+8, w+16, w+24
// (4 serial iters/wave — halved serial critical path vs r7).
__global__ __launch_bounds__(512) void k_logits(
    const float* __restrict__ hg, const float* __restrict__ pvec,
    const float* __restrict__ invn,
    const short* __restrict__ wa_bf, const float* __restrict__ wjf,
    const float* __restrict__ wpf, const float* __restrict__ coords,
    const float* __restrict__ We2, const float* __restrict__ be2,
    const float* __restrict__ s_sl, const float* __restrict__ s_ps,
    const float* __restrict__ s_ss,
    float* __restrict__ logits){
  int blk = blockIdx.x;
  int b = blk >> 9, i = blk & (NN-1);
  int tid  = threadIdx.x;
  int w    = tid >> 6;
  int lane = tid & 63;
  int q    = lane & 15;
  int kg   = lane >> 4;

  __shared__ __align__(16) float s_hi[64];
  __shared__ __align__(16) float s_pv[64];
  __shared__ __align__(16) float s_prior[NN];
  __shared__ __align__(16) float s_invn[NN];

  float spsl  = softplusf(s_sl[0]);
  float spps  = softplusf(s_ps[0]);
  float spss  = softplusf(s_ss[0]);

  if (tid < 64){
    s_hi[tid] = hg  [(b*NN + i)*64 + tid];
    s_pv[tid] = pvec[(b*NN + i)*64 + tid];
  }
  {
    float4 ci0 = *(const float4*)(coords + i*NC);
    float4 ci1 = *(const float4*)(coords + i*NC + 4);
    int j = tid;                           // 512 threads -> 1 j each
    float4 cj0 = *(const float4*)(coords + j*NC);
    float4 cj1 = *(const float4*)(coords + j*NC + 4);
    float dd = 0.f;
    dd = fmaf(ci0.x-cj0.x, ci0.x-cj0.x, dd);
    dd = fmaf(ci0.y-cj0.y, ci0.y-cj0.y, dd);
    dd = fmaf(ci0.z-cj0.z, ci0.z-cj0.z, dd);
    dd = fmaf(ci0.w-cj0.w, ci0.w-cj0.w, dd);
    dd = fmaf(ci1.x-cj1.x, ci1.x-cj1.x, dd);
    dd = fmaf(ci1.y-cj1.y, ci1.y-cj1.y, dd);
    dd = fmaf(ci1.z-cj1.z, ci1.z-cj1.z, dd);
    dd = fmaf(ci1.w-cj1.w, ci1.w-cj1.w, dd);
    float dist = sqrtf(fmaxf(dd, 1e-12f));
    s_prior[j] = (j == i) ? 0.f : spps / (1.f + dist);
    s_invn[j]  = invn[b*NN + j];
  }
  __syncthreads();

  float hiA[16];
  {
    float4 t0 = *(const float4*)(s_hi + kg*8);
    float4 t1 = *(const float4*)(s_hi + kg*8 + 4);
    float4 t2 = *(const float4*)(s_hi + 32 + kg*8);
    float4 t3 = *(const float4*)(s_hi + 32 + kg*8 + 4);
    hiA[0]=t0.x; hiA[1]=t0.y; hiA[2]=t0.z; hiA[3]=t0.w;
    hiA[4]=t1.x; hiA[5]=t1.y; hiA[6]=t1.z; hiA[7]=t1.w;
    hiA[8]=t2.x; hiA[9]=t2.y; hiA[10]=t2.z; hiA[11]=t2.w;
    hiA[12]=t3.x; hiA[13]=t3.y; hiA[14]=t3.z; hiA[15]=t3.w;
  }

  short8 wa[2][4];
  #pragma unroll
  for (int ks = 0; ks < 2; ++ks)
    #pragma unroll
    for (int nt = 0; nt < 4; ++nt){
      wa[ks][nt] = *(const short8*)(wa_bf + ((ks*4 + nt)*64 + lane)*8);
      keep8(wa[ks][nt]);
    }

  short8 cw[2][4];
  #pragma unroll
  for (int ks2 = 0; ks2 < 2; ++ks2)
    #pragma unroll
    for (int nt = 0; nt < 4; ++nt){
      const float* wj = wjf + ((ks2*4 + nt)*64 + lane)*8;
      const float* wp = wpf + ((ks2*4 + nt)*64 + lane)*8;
      float4 j0 = *(const float4*)(wj);
      float4 j1 = *(const float4*)(wj + 4);
      float4 p0 = *(const float4*)(wp);
      float4 p1 = *(const float4*)(wp + 4);
      int hb = ks2*8;
      uint4v u;
      u[0] = cvtpk(fmaf(hiA[hb+0], p0.x, j0.x), fmaf(hiA[hb+1], p0.y, j0.y));
      u[1] = cvtpk(fmaf(hiA[hb+2], p0.z, j0.z), fmaf(hiA[hb+3], p0.w, j0.w));
      u[2] = cvtpk(fmaf(hiA[hb+4], p1.x, j1.x), fmaf(hiA[hb+5], p1.y, j1.y));
      u[3] = cvtpk(fmaf(hiA[hb+6], p1.z, j1.z), fmaf(hiA[hb+7], p1.w, j1.w));
      cw[ks2][nt] = __builtin_bit_cast(short8, u);
    }

  float pv4[4], we2q[4];
  #pragma unroll
  for (int nt = 0; nt < 4; ++nt){
    pv4[nt]  = s_pv[nt*16 + q];
    we2q[nt] = We2[nt*16 + q];
  }
  float invni = invn[b*NN + i];
  float be2v  = be2[0];
  int   srcl  = (lane & 48) | (((lane >> 4) & 3) << 2) | (lane & 3);
  float* lrowg = logits + (size_t)(b*NN + i) * NN;

  #pragma unroll
  for (int s = 0; s < 4; ++s){
    int it = w + s*8;
    int jbase = it * 16;
    float4 hj0, hj1, hj2, hj3;
    {
      const float* hjp = hg + (size_t)(b*NN + jbase + q)*64 + kg*8;
      hj0 = *(const float4*)(hjp);
      hj1 = *(const float4*)(hjp + 4);
      hj2 = *(const float4*)(hjp + 32);
      hj3 = *(const float4*)(hjp + 36);
    }
    float hjA[16];
    hjA[0]=hj0.x; hjA[1]=hj0.y; hjA[2]=hj0.z; hjA[3]=hj0.w;
    hjA[4]=hj1.x; hjA[5]=hj1.y; hjA[6]=hj1.z; hjA[7]=hj1.w;
    hjA[8]=hj2.x; hjA[9]=hj2.y; hjA[10]=hj2.z; hjA[11]=hj2.w;
    hjA[12]=hj3.x; hjA[13]=hj3.y; hjA[14]=hj3.z; hjA[15]=hj3.w;

    uint4v u0, u1, u2, u3;
    float dotp = 0.f;
    #pragma unroll
    for (int w2 = 0; w2 < 4; ++w2){
      int e0 = 2*w2, e1 = 2*w2 + 1;
      u0[w2] = cvtpk(fabsf(hiA[e0]   - hjA[e0]),  fabsf(hiA[e1]   - hjA[e1]));
      u1[w2] = cvtpk(fabsf(hiA[8+e0] - hjA[8+e0]), fabsf(hiA[8+e1] - hjA[8+e1]));
      u2[w2] = cvtpk(hjA[e0],   hjA[e1]);
      u3[w2] = cvtpk(hjA[8+e0], hjA[8+e1]);
      dotp = fmaf(hiA[e0],   hjA[e0],   dotp);
      dotp = fmaf(hiA[e1],   hjA[e1],   dotp);
      dotp = fmaf(hiA[8+e0], hjA[8+e0], dotp);
      dotp = fmaf(hiA[8+e1], hjA[8+e1], dotp);
    }
    short8 af0 = __builtin_bit_cast(short8, u0);
    short8 af1 = __builtin_bit_cast(short8, u1);
    short8 af2 = __builtin_bit_cast(short8, u2);
    short8 af3 = __builtin_bit_cast(short8, u3);

    f32x4 acc[4];
    #pragma unroll
    for (int nt = 0; nt < 4; ++nt)
      acc[nt] = (f32x4){pv4[nt], pv4[nt], pv4[nt], pv4[nt]};
    #pragma unroll
    for (int nt = 0; nt < 4; ++nt){
      acc[nt] = __builtin_amdgcn_mfma_f32_16x16x32_bf16(af0, wa[0][nt], acc[nt], 0, 0, 0);
      acc[nt] = __builtin_amdgcn_mfma_f32_16x16x32_bf16(af1, wa[1][nt], acc[nt], 0, 0, 0);
      acc[nt] = __builtin_amdgcn_mfma_f32_16x16x32_bf16(af2, cw[0][nt], acc[nt], 0, 0, 0);
      acc[nt] = __builtin_amdgcn_mfma_f32_16x16x32_bf16(af3, cw[1][nt], acc[nt], 0, 0, 0);
    }

    float part[4] = {0.f, 0.f, 0.f, 0.f};
    #pragma unroll
    for (int nt = 0; nt < 4; ++nt)
      #pragma unroll
      for (int r = 0; r < 4; ++r)
        part[r] = fmaf(fmaxf(acc[nt][r], 0.f), we2q[nt], part[r]);
    #pragma unroll
    for (int r = 0; r < 4; ++r) part[r] = row16_sum(part[r]);

    dotp += __shfl_xor(dotp, 16);
    dotp += __shfl_xor(dotp, 32);
    float dj = __shfl(dotp, srcl);

    if (q < 4){
      int j2 = jbase + kg*4 + q;
      float ps = part[0];
      ps = (q == 1) ? part[1] : ps;
      ps = (q == 2) ? part[2] : ps;
      ps = (q == 3) ? part[3] : ps;
      float cosv = dj * invni * s_invn[j2];
      float ev   = ps + be2v + s_prior[j2];
      lrowg[j2] = (j2 == i) ? spsl : fmaf(spss, cosv, ev);
    }
  }
}

// ---------------- Kernel S: row softmax logits -> unsym ----------------
__global__ __launch_bounds__(256) void k_soft(
    const float* __restrict__ logits, const float* __restrict__ s_tp,
    float* __restrict__ unsym){
  int blk = blockIdx.x;
  int tid = threadIdx.x;
  int lane = tid & 63, w = tid >> 6;
  float invt = 1.f / (softplusf(s_tp[0]) + 1e-4f);

  const float* row = logits + (size_t)blk * NN;
  float2 v = *(const float2*)(row + tid*2);

  __shared__ float red[8];
  float m1 = fmaxf(v.x, v.y);
  #pragma unroll
  for (int msk = 1; msk < 64; msk <<= 1) m1 = fmaxf(m1, __shfl_xor(m1, msk));
  if (lane == 0) red[w] = m1;
  __syncthreads();
  m1 = fmaxf(fmaxf(red[0], red[1]), fmaxf(red[2], red[3]));

  float e0 = expf((v.x - m1) * invt);
  float e1 = expf((v.y - m1) * invt);
  float se = e0 + e1;
  #pragma unroll
  for (int msk = 1; msk < 64; msk <<= 1) se += __shfl_xor(se, msk);
  if (lane == 0) red[4 + w] = se;
  __syncthreads();
  se = red[4] + red[5] + red[6] + red[7];
  float inv_se = 1.f / se;

  float* urow = unsym + (size_t)blk * NN;
  *(float2*)(urow + tid*2) = (float2){e0 * inv_se, e1 * inv_se};
}

// ---------------- Kernel D: symmetrize + renormalize ----------------
__global__ __launch_bounds__(256) void k_sym(
    const float* __restrict__ u, float* __restrict__ out){
  int blk = blockIdx.x;
  int b = blk >> 9, i = blk & (NN-1);
  int tid = threadIdx.x;
  const float* urow = u + (size_t)(b*NN + i) * NN;
  float v0, v1, rs;
  {
    int j0 = tid, j1 = tid + 256;
    float a1 = urow[j0];
    float a2 = u[(size_t)(b*NN + j0) * NN + i];
    v0 = 0.5f*(a1 + a2);
    float a3 = urow[j1];
    float a4 = u[(size_t)(b*NN + j1) * NN + i];
    v1 = 0.5f*(a3 + a4);
    rs = v0 + v1;
  }
  int lane = tid & 63, w = tid >> 6;
  #pragma unroll
  for (int msk = 1; msk < 64; msk <<= 1) rs += __shfl_xor(rs, msk);
  __shared__ float red[4];
  if (lane == 0) red[w] = rs;
  __syncthreads();
  rs = red[0] + red[1] + red[2] + red[3];
  float inv = 1.f / fmaxf(rs, 1e-6f);
  float* orow = out + (size_t)(b*NN + i) * NN;
  orow[tid]       = v0 * inv;
  orow[tid + 256] = v1 * inv;
}

extern "C" void kernel_launch(void* const* d_in, const int* in_sizes, int n_in,
                              void* d_out, int out_size, void* d_ws, size_t ws_size,
                              hipStream_t stream){
  const float* x      = (const float*)d_in[0];
  const float* mask   = (const float*)d_in[1];
  const float* sctx   = (const float*)d_in[2];
  const float* coords = (const float*)d_in[3];
  const float* W1     = (const float*)d_in[4];
  const float* b1     = (const float*)d_in[5];
  const float* W2     = (const float*)d_in[6];
  const float* b2     = (const float*)d_in[7];
  const float* We1    = (const float*)d_in[8];
  const float* be1    = (const float*)d_in[9];
  const float* We2    = (const float*)d_in[10];
  const float* be2    = (const float*)d_in[11];
  const float* sl     = (const float*)d_in[12];
  const float* ps     = (const float*)d_in[13];
  const float* ss     = (const float*)d_in[14];
  const float* tp     = (const float*)d_in[15];

  float* ws     = (float*)d_ws;
  float* hgp    = ws + OFF_H;
  float* pvecp  = ws + OFF_PVEC;
  float* invnp  = ws + OFF_INVN;
  short* wabfp  = (short*)(ws + OFF_WA);
  float* wjfp   = ws + OFF_WJF;
  float* wpfp   = ws + OFF_WPF;
  float* unsym  = ws + OFF_UNSYM;
  float* logit  = ws + OFF_LOGIT;
  float* out    = (float*)d_out;

  k_front <<<304, 256, 0, stream>>>(x, mask, sctx, W1, b1, W2, b2, We1, be1,
                                    hgp, pvecp, invnp, wabfp, wjfp, wpfp);
  k_logits<<<NB*NN, 512, 0, stream>>>(hgp, pvecp, invnp, wabfp, wjfp, wpfp,
                                      coords, We2, be2, sl, ps, ss, logit);
  k_soft  <<<NB*NN, 256, 0, stream>>>(logit, tp, unsym);
  k_sym   <<<NB*NN, 256, 0, stream>>>(unsym, out);
}